// Round 1
// baseline (1517.520 us; speedup 1.0000x reference)
//
#include <hip/hip_runtime.h>
#include <stdint.h>

#define DEPTH 4
#define BATCH 8
#define NN 2048
#define ZDIM 512
#define SDIM 64
#define MLPD 2048
#define ROWS (BATCH*NN)   // 16384

typedef __bf16 bf16x8_t __attribute__((ext_vector_type(8)));
typedef float f32x4_t __attribute__((ext_vector_type(4)));

#define AS1 __attribute__((address_space(1)))
#define AS3 __attribute__((address_space(3)))

__device__ __forceinline__ void gload16(const void* g, void* l) {
  __builtin_amdgcn_global_load_lds((const AS1 void*)g, (AS3 void*)l, 16, 0, 0);
}

__device__ __forceinline__ unsigned short f2bf(float f) {
  union { float f; unsigned u; } v; v.f = f;
  unsigned u = v.u;
  unsigned r = (u + 0x7fffu + ((u >> 16) & 1u)) >> 16;
  return (unsigned short)r;
}
__device__ __forceinline__ float bf2f(unsigned short h) {
  union { unsigned u; float f; } v; v.u = ((unsigned)h) << 16;
  return v.f;
}

// ---- convert spatial embedding rows to bf16 + squared norms (from bf16 values,
// so that d2_ii == 0 exactly against the MFMA Gram diagonal) -------------------
__global__ __launch_bounds__(256) void conv_e_kernel(const float* __restrict__ s,
    unsigned short* __restrict__ ebf, float* __restrict__ sq) {
  int lane = threadIdx.x & 63;
  int row = blockIdx.x * 4 + (threadIdx.x >> 6);
  float x = s[(long)row * SDIM + lane];
  unsigned short v = f2bf(x);
  ebf[(long)row * SDIM + lane] = v;
  float xb = bf2f(v);
  float ss = xb * xb;
  #pragma unroll
  for (int off = 32; off > 0; off >>= 1) ss += __shfl_xor(ss, off);
  if (lane == 0) sq[row] = ss;
}

// ---- transpose + f32->bf16: in [R][C] f32 -> out [C][R] bf16, batched --------
__global__ __launch_bounds__(256) void tconv_kernel(const float* __restrict__ in,
    unsigned short* __restrict__ out, int R, int C, long sIn, long sOut) {
  __shared__ float tile[32][33];
  int b = blockIdx.z;
  int c0 = blockIdx.x * 32, r0 = blockIdx.y * 32;
  int tx = threadIdx.x, ty = threadIdx.y;
  const float* ib = in + (long)b * sIn;
  unsigned short* ob = out + (long)b * sOut;
  #pragma unroll
  for (int i = 0; i < 32; i += 8)
    tile[ty + i][tx] = ib[(long)(r0 + ty + i) * C + c0 + tx];
  __syncthreads();
  #pragma unroll
  for (int i = 0; i < 32; i += 8)
    ob[(long)(c0 + ty + i) * R + r0 + tx] = f2bf(tile[tx][ty + i]);
}

// ---- LayerNorm over D=512, write bf16 normalized rows ------------------------
__global__ __launch_bounds__(256) void ln_kernel(const float* __restrict__ x,
    const float* __restrict__ scale, const float* __restrict__ bias,
    unsigned short* __restrict__ y) {
  int lane = threadIdx.x & 63;
  long row = (long)blockIdx.x * 4 + (threadIdx.x >> 6);
  const float* xr = x + row * ZDIM + lane * 8;
  float4 v0 = *(const float4*)xr;
  float4 v1 = *(const float4*)(xr + 4);
  float xv[8] = {v0.x, v0.y, v0.z, v0.w, v1.x, v1.y, v1.z, v1.w};
  float s1 = 0.f, s2 = 0.f;
  #pragma unroll
  for (int k = 0; k < 8; ++k) { s1 += xv[k]; s2 += xv[k] * xv[k]; }
  #pragma unroll
  for (int off = 32; off > 0; off >>= 1) {
    s1 += __shfl_xor(s1, off);
    s2 += __shfl_xor(s2, off);
  }
  float mean = s1 * (1.0f / ZDIM);
  float var = s2 * (1.0f / ZDIM) - mean * mean;
  float rstd = rsqrtf(var + 1e-5f);
  const float* sc = scale + lane * 8;
  const float* bi = bias + lane * 8;
  alignas(16) unsigned short o[8];
  #pragma unroll
  for (int k = 0; k < 8; ++k)
    o[k] = f2bf((xv[k] - mean) * rstd * sc[k] + bi[k]);
  *(uint4*)(y + row * ZDIM + lane * 8) = *(const uint4*)o;
}

// ---- attention weights: w = exp(-max(sq_i+sq_j-2*e_i.e_j,0)), plus 1/rowsum --
// grid (NN/64, BATCH), 256 thr. Wave w owns 16 i-rows; loops j in tiles of 128.
__global__ __launch_bounds__(256) void attn_w_kernel(const unsigned short* __restrict__ ebf,
    const float* __restrict__ sq, unsigned short* __restrict__ wout,
    float* __restrict__ invrs) {
  __shared__ unsigned short Ei[64 * 64];
  __shared__ unsigned short Ej[128 * 64];
  int tid = threadIdx.x, lane = tid & 63, wid = tid >> 6;
  int b = blockIdx.y;
  int i0 = blockIdx.x * 64;
  const unsigned short* eb = ebf + (long)b * NN * SDIM;

  #pragma unroll
  for (int it = 0; it < 2; ++it) {
    int c = it * 256 + tid;
    int r = c >> 3, c8 = c & 7;
    gload16(eb + (long)(i0 + r) * SDIM + c8 * 8, Ei + (it * 256 + (tid & 192)) * 8);
  }
  __syncthreads();
  bf16x8_t afrag[2];
  #pragma unroll
  for (int s2i = 0; s2i < 2; ++s2i)
    afrag[s2i] = *(const bf16x8_t*)&Ei[(wid * 16 + (lane & 15)) * 64 + s2i * 32 + (lane >> 4) * 8];
  int rloc = wid * 16 + ((lane >> 4) << 2);
  float sqi[4];
  #pragma unroll
  for (int r = 0; r < 4; ++r) sqi[r] = sq[b * NN + i0 + rloc + r];
  float rs[4] = {0.f, 0.f, 0.f, 0.f};

  for (int j0 = 0; j0 < NN; j0 += 128) {
    __syncthreads();
    #pragma unroll
    for (int it = 0; it < 4; ++it) {
      int c = it * 256 + tid;
      int r = c >> 3, c8 = c & 7;
      gload16(eb + (long)(j0 + r) * SDIM + c8 * 8, Ej + (it * 256 + (tid & 192)) * 8);
    }
    __syncthreads();
    #pragma unroll
    for (int n = 0; n < 8; ++n) {
      f32x4_t g = {0.f, 0.f, 0.f, 0.f};
      #pragma unroll
      for (int s2i = 0; s2i < 2; ++s2i) {
        bf16x8_t bfr = *(const bf16x8_t*)&Ej[(n * 16 + (lane & 15)) * 64 + s2i * 32 + (lane >> 4) * 8];
        g = __builtin_amdgcn_mfma_f32_16x16x32_bf16(afrag[s2i], bfr, g, 0, 0, 0);
      }
      int col = j0 + n * 16 + (lane & 15);
      float sqj = sq[b * NN + col];
      #pragma unroll
      for (int r = 0; r < 4; ++r) {
        float d2 = sqi[r] + sqj - 2.0f * g[r];
        d2 = fmaxf(d2, 0.0f);
        float w = __expf(-d2);
        unsigned short wb = f2bf(w);
        rs[r] += bf2f(wb);
        wout[(long)b * NN * NN + (long)(i0 + rloc + r) * NN + col] = wb;
      }
    }
  }
  #pragma unroll
  for (int off = 1; off < 16; off <<= 1) {
    #pragma unroll
    for (int r = 0; r < 4; ++r) rs[r] += __shfl_xor(rs[r], off);
  }
  if ((lane & 15) == 0) {
    #pragma unroll
    for (int r = 0; r < 4; ++r) invrs[b * NN + i0 + rloc + r] = 1.0f / rs[r];
  }
}

// ---- 128x128 MFMA GEMM (m97 structure): C = A[M,K] @ BT[N,K]^T ---------------
// EPI 0: f32 out, scale row by invrs (PV).  EPI 1: bf16 out, bias+exact GELU.
// EPI 2: f32 out, bias + residual add.
template <int EPI>
__global__ __launch_bounds__(256) void gemm128(
    const unsigned short* __restrict__ A, const unsigned short* __restrict__ BT,
    void* __restrict__ Cout, const float* __restrict__ bias,
    const float* __restrict__ resid, const float* __restrict__ invrs,
    int M, int Nmat, int K, long sA, long sB, long sC, long sR) {
  __shared__ unsigned short As[128 * 64];
  __shared__ unsigned short Bs[128 * 64];
  int tid = threadIdx.x, lane = tid & 63;
  int bj = blockIdx.x, bi = blockIdx.y, bb = blockIdx.z;
  const unsigned short* Ab = A + (long)bb * sA;
  const unsigned short* Bb = BT + (long)bb * sB;
  int row0 = bi * 128, col0 = bj * 128;
  int wid = tid >> 6, wr = wid >> 1, wc = wid & 1;
  const f32x4_t fzero = {0.f, 0.f, 0.f, 0.f};
  f32x4_t acc[4][4];
  #pragma unroll
  for (int m = 0; m < 4; ++m)
    #pragma unroll
    for (int n = 0; n < 4; ++n) acc[m][n] = fzero;

  for (int k0 = 0; k0 < K; k0 += 64) {
    #pragma unroll
    for (int it = 0; it < 4; ++it) {
      int c = it * 256 + tid;
      int r = c >> 3, c8 = c & 7;
      gload16(Ab + (long)(row0 + r) * K + k0 + c8 * 8, As + (it * 256 + (tid & 192)) * 8);
      int rr = col0 + r;
      if (rr >= Nmat) rr = Nmat - 1;  // N=64 tail: read valid garbage, masked on store
      gload16(Bb + (long)rr * K + k0 + c8 * 8, Bs + (it * 256 + (tid & 192)) * 8);
    }
    __syncthreads();
    #pragma unroll
    for (int s2i = 0; s2i < 2; ++s2i) {
      bf16x8_t a[4], bfr[4];
      int lr = lane & 15, lk = s2i * 32 + (lane >> 4) * 8;
      #pragma unroll
      for (int m = 0; m < 4; ++m)
        a[m] = *(const bf16x8_t*)&As[(wr * 64 + m * 16 + lr) * 64 + lk];
      #pragma unroll
      for (int n = 0; n < 4; ++n)
        bfr[n] = *(const bf16x8_t*)&Bs[(wc * 64 + n * 16 + lr) * 64 + lk];
      #pragma unroll
      for (int m = 0; m < 4; ++m)
        #pragma unroll
        for (int n = 0; n < 4; ++n)
          acc[m][n] = __builtin_amdgcn_mfma_f32_16x16x32_bf16(a[m], bfr[n], acc[m][n], 0, 0, 0);
    }
    __syncthreads();
  }

  int rbase = row0 + wr * 64 + ((lane >> 4) << 2);
  int cbase = col0 + wc * 64 + (lane & 15);
  #pragma unroll
  for (int n = 0; n < 4; ++n) {
    int col = cbase + n * 16;
    if (col >= Nmat) continue;
    float bv = (EPI != 0) ? bias[col] : 0.f;
    #pragma unroll
    for (int m = 0; m < 4; ++m) {
      #pragma unroll
      for (int r = 0; r < 4; ++r) {
        int row = rbase + m * 16 + r;
        float v = acc[m][n][r];
        long cidx = (long)bb * sC + (long)row * Nmat + col;
        if (EPI == 0) {
          v *= invrs[(long)bb * sR + row];
          ((float*)Cout)[cidx] = v;
        } else if (EPI == 1) {
          v += bv;
          v = 0.5f * v * (1.0f + erff(v * 0.70710678118654752440f));
          ((unsigned short*)Cout)[cidx] = f2bf(v);
        } else {
          v += bv + resid[(long)bb * sR + (long)row * Nmat + col];
          ((float*)Cout)[cidx] = v;
        }
      }
    }
  }
}

extern "C" void kernel_launch(void* const* d_in, const int* in_sizes, int n_in,
                              void* d_out, int out_size, void* d_ws, size_t ws_size,
                              hipStream_t stream) {
  (void)in_sizes; (void)n_in; (void)out_size; (void)ws_size;
  const float* in_z   = (const float*)d_in[0];
  const float* in_s   = (const float*)d_in[1];
  const float* lnz_sc = (const float*)d_in[2];
  const float* lnz_bi = (const float*)d_in[3];
  const float* lns_sc = (const float*)d_in[4];
  const float* lns_bi = (const float*)d_in[5];
  const float* Wz1 = (const float*)d_in[6];
  const float* bz1 = (const float*)d_in[7];
  const float* Wz2 = (const float*)d_in[8];
  const float* bz2 = (const float*)d_in[9];
  const float* Ws1 = (const float*)d_in[10];
  const float* bs1 = (const float*)d_in[11];
  const float* Ws2 = (const float*)d_in[12];
  const float* bs2 = (const float*)d_in[13];
  float* out_z = (float*)d_out;
  float* out_s = out_z + (long)ROWS * ZDIM;

  // workspace layout (~200.4 MB)
  char* ws = (char*)d_ws;
  size_t off = 0;
  auto alloc = [&](size_t bytes) { void* p = ws + off; off += (bytes + 255) & ~(size_t)255; return p; };
  unsigned short* WH   = (unsigned short*)alloc((size_t)BATCH * NN * NN * 2); // w / h aliased (67MB)
  unsigned short* ZT   = (unsigned short*)alloc((size_t)BATCH * ZDIM * NN * 2);
  unsigned short* XLN  = (unsigned short*)alloc((size_t)ROWS * ZDIM * 2);
  unsigned short* EBF  = (unsigned short*)alloc((size_t)ROWS * SDIM * 2);
  float* ZATT = (float*)alloc((size_t)ROWS * ZDIM * 4);
  float* ZBUF = (float*)alloc((size_t)ROWS * ZDIM * 4);
  float* SBUF = (float*)alloc((size_t)ROWS * SDIM * 4);
  float* SQ   = (float*)alloc((size_t)ROWS * 4);
  float* IRS  = (float*)alloc((size_t)ROWS * 4);
  unsigned short* W1Z = (unsigned short*)alloc((size_t)DEPTH * MLPD * ZDIM * 2);
  unsigned short* W2Z = (unsigned short*)alloc((size_t)DEPTH * ZDIM * MLPD * 2);
  unsigned short* W1S = (unsigned short*)alloc((size_t)DEPTH * MLPD * ZDIM * 2);
  unsigned short* W2S = (unsigned short*)alloc((size_t)DEPTH * SDIM * MLPD * 2);

  // weight transpose+convert (B^T layout [N][K] for MFMA B-operand)
  tconv_kernel<<<dim3(MLPD / 32, ZDIM / 32, DEPTH), dim3(32, 8), 0, stream>>>(
      Wz1, W1Z, ZDIM, MLPD, (long)ZDIM * MLPD, (long)MLPD * ZDIM);
  tconv_kernel<<<dim3(ZDIM / 32, MLPD / 32, DEPTH), dim3(32, 8), 0, stream>>>(
      Wz2, W2Z, MLPD, ZDIM, (long)MLPD * ZDIM, (long)ZDIM * MLPD);
  tconv_kernel<<<dim3(MLPD / 32, ZDIM / 32, DEPTH), dim3(32, 8), 0, stream>>>(
      Ws1, W1S, ZDIM, MLPD, (long)ZDIM * MLPD, (long)MLPD * ZDIM);
  tconv_kernel<<<dim3(SDIM / 32, MLPD / 32, DEPTH), dim3(32, 8), 0, stream>>>(
      Ws2, W2S, MLPD, SDIM, (long)MLPD * SDIM, (long)SDIM * MLPD);

  for (int L = 0; L < DEPTH; ++L) {
    const float* z_in = (L == 0) ? in_z : ZBUF;
    const float* s_in = (L == 0) ? in_s : SBUF;
    float* z_out = (L == DEPTH - 1) ? out_z : ZBUF;
    float* s_out = (L == DEPTH - 1) ? out_s : SBUF;

    conv_e_kernel<<<ROWS / 4, 256, 0, stream>>>(s_in, EBF, SQ);
    tconv_kernel<<<dim3(ZDIM / 32, NN / 32, BATCH), dim3(32, 8), 0, stream>>>(
        z_in, ZT, NN, ZDIM, (long)NN * ZDIM, (long)ZDIM * NN);
    attn_w_kernel<<<dim3(NN / 64, BATCH), 256, 0, stream>>>(EBF, SQ, WH, IRS);
    // z_att = (w @ z) / rowsum
    gemm128<0><<<dim3(ZDIM / 128, NN / 128, BATCH), 256, 0, stream>>>(
        WH, ZT, ZATT, nullptr, nullptr, IRS,
        NN, ZDIM, NN, (long)NN * NN, (long)ZDIM * NN, (long)NN * ZDIM, NN);
    // z-FF
    ln_kernel<<<ROWS / 4, 256, 0, stream>>>(ZATT, lnz_sc + L * ZDIM, lnz_bi + L * ZDIM, XLN);
    gemm128<1><<<dim3(MLPD / 128, ROWS / 128, 1), 256, 0, stream>>>(
        XLN, W1Z + (long)L * MLPD * ZDIM, WH, bz1 + L * MLPD, nullptr, nullptr,
        ROWS, MLPD, ZDIM, 0, 0, 0, 0);
    gemm128<2><<<dim3(ZDIM / 128, ROWS / 128, 1), 256, 0, stream>>>(
        WH, W2Z + (long)L * ZDIM * MLPD, z_out, bz2 + L * ZDIM, ZATT, nullptr,
        ROWS, ZDIM, MLPD, 0, 0, 0, 0);
    // s-FF
    ln_kernel<<<ROWS / 4, 256, 0, stream>>>(z_out, lns_sc + L * ZDIM, lns_bi + L * ZDIM, XLN);
    gemm128<1><<<dim3(MLPD / 128, ROWS / 128, 1), 256, 0, stream>>>(
        XLN, W1S + (long)L * MLPD * ZDIM, WH, bs1 + L * MLPD, nullptr, nullptr,
        ROWS, MLPD, ZDIM, 0, 0, 0, 0);
    gemm128<2><<<dim3(1, ROWS / 128, 1), 256, 0, stream>>>(
        WH, W2S + (long)L * SDIM * MLPD, s_out, bs2 + L * SDIM, s_in, nullptr,
        ROWS, SDIM, MLPD, 0, 0, 0, 0);
  }
}

// Round 2
// 1488.226 us; speedup vs baseline: 1.0197x; 1.0197x over previous
//
#include <hip/hip_runtime.h>
#include <stdint.h>

#define DEPTH 4
#define BATCH 8
#define NN 2048
#define ZDIM 512
#define SDIM 64
#define MLPD 2048
#define ROWS (BATCH*NN)   // 16384

typedef __bf16 bf16x8_t __attribute__((ext_vector_type(8)));
typedef float f32x4_t __attribute__((ext_vector_type(4)));

#define AS1 __attribute__((address_space(1)))
#define AS3 __attribute__((address_space(3)))

__device__ __forceinline__ void gload16(const void* g, void* l) {
  __builtin_amdgcn_global_load_lds((const AS1 void*)g, (AS3 void*)l, 16, 0, 0);
}

__device__ __forceinline__ unsigned short f2bf(float f) {
  union { float f; unsigned u; } v; v.f = f;
  unsigned u = v.u;
  unsigned r = (u + 0x7fffu + ((u >> 16) & 1u)) >> 16;
  return (unsigned short)r;
}
__device__ __forceinline__ float bf2f(unsigned short h) {
  union { unsigned u; float f; } v; v.u = ((unsigned)h) << 16;
  return v.f;
}

// exact-erf GELU via Abramowitz-Stegun 7.1.26 (max abs err 1.5e-7, ~12 VALU ops)
__device__ __forceinline__ float gelu_fast(float x) {
  float ax = fabsf(x) * 0.70710678118654752440f;
  float t = __builtin_amdgcn_rcpf(1.0f + 0.3275911f * ax);
  float p = t * (0.254829592f + t * (-0.284496736f + t * (1.421413741f +
            t * (-1.453152027f + t * 1.061405429f))));
  float er = 1.0f - p * __expf(-ax * ax);      // erf(|x|/sqrt2)
  float s = (x >= 0.f) ? er : -er;
  return 0.5f * x * (1.0f + s);
}

// ---- convert spatial embedding rows to bf16 + squared norms ------------------
__global__ __launch_bounds__(256) void conv_e_kernel(const float* __restrict__ s,
    unsigned short* __restrict__ ebf, float* __restrict__ sq) {
  int lane = threadIdx.x & 63;
  int row = blockIdx.x * 4 + (threadIdx.x >> 6);
  float x = s[(long)row * SDIM + lane];
  unsigned short v = f2bf(x);
  ebf[(long)row * SDIM + lane] = v;
  float xb = bf2f(v);
  float ss = xb * xb;
  #pragma unroll
  for (int off = 32; off > 0; off >>= 1) ss += __shfl_xor(ss, off);
  if (lane == 0) sq[row] = ss;
}

// ---- transpose + f32->bf16: in [R][C] f32 -> out [C][R] bf16, batched --------
__global__ __launch_bounds__(256) void tconv_kernel(const float* __restrict__ in,
    unsigned short* __restrict__ out, int R, int C, long sIn, long sOut) {
  __shared__ float tile[32][33];
  int b = blockIdx.z;
  int c0 = blockIdx.x * 32, r0 = blockIdx.y * 32;
  int tx = threadIdx.x, ty = threadIdx.y;
  const float* ib = in + (long)b * sIn;
  unsigned short* ob = out + (long)b * sOut;
  #pragma unroll
  for (int i = 0; i < 32; i += 8)
    tile[ty + i][tx] = ib[(long)(r0 + ty + i) * C + c0 + tx];
  __syncthreads();
  #pragma unroll
  for (int i = 0; i < 32; i += 8)
    ob[(long)(c0 + ty + i) * R + r0 + tx] = f2bf(tile[tx][ty + i]);
}

// ---- LayerNorm over D=512, write bf16 normalized rows ------------------------
__global__ __launch_bounds__(256) void ln_kernel(const float* __restrict__ x,
    const float* __restrict__ scale, const float* __restrict__ bias,
    unsigned short* __restrict__ y) {
  int lane = threadIdx.x & 63;
  long row = (long)blockIdx.x * 4 + (threadIdx.x >> 6);
  const float* xr = x + row * ZDIM + lane * 8;
  float4 v0 = *(const float4*)xr;
  float4 v1 = *(const float4*)(xr + 4);
  float xv[8] = {v0.x, v0.y, v0.z, v0.w, v1.x, v1.y, v1.z, v1.w};
  float s1 = 0.f, s2 = 0.f;
  #pragma unroll
  for (int k = 0; k < 8; ++k) { s1 += xv[k]; s2 += xv[k] * xv[k]; }
  #pragma unroll
  for (int off = 32; off > 0; off >>= 1) {
    s1 += __shfl_xor(s1, off);
    s2 += __shfl_xor(s2, off);
  }
  float mean = s1 * (1.0f / ZDIM);
  float var = s2 * (1.0f / ZDIM) - mean * mean;
  float rstd = rsqrtf(var + 1e-5f);
  const float* sc = scale + lane * 8;
  const float* bi = bias + lane * 8;
  alignas(16) unsigned short o[8];
  #pragma unroll
  for (int k = 0; k < 8; ++k)
    o[k] = f2bf((xv[k] - mean) * rstd * sc[k] + bi[k]);
  *(uint4*)(y + row * ZDIM + lane * 8) = *(const uint4*)o;
}

// ---- attention weights: w = exp(-max(sq_i+sq_j-2*e_i.e_j,0)), plus 1/rowsum --
__global__ __launch_bounds__(256) void attn_w_kernel(const unsigned short* __restrict__ ebf,
    const float* __restrict__ sq, unsigned short* __restrict__ wout,
    float* __restrict__ invrs) {
  __shared__ unsigned short Ei[64 * 64];
  __shared__ unsigned short Ej[2][128 * 64];
  int tid = threadIdx.x, lane = tid & 63, wid = tid >> 6;
  int b = blockIdx.y;
  int i0 = blockIdx.x * 64;
  const unsigned short* eb = ebf + (long)b * NN * SDIM;

  #pragma unroll
  for (int it = 0; it < 2; ++it) {
    int c = it * 256 + tid;
    int r = c >> 3, c8 = c & 7;
    gload16(eb + (long)(i0 + r) * SDIM + c8 * 8, Ei + (it * 256 + (tid & 192)) * 8);
  }
  auto stageEj = [&](int buf, int j0) {
    #pragma unroll
    for (int it = 0; it < 4; ++it) {
      int c = it * 256 + tid;
      int r = c >> 3, c8 = c & 7;
      gload16(eb + (long)(j0 + r) * SDIM + c8 * 8, &Ej[buf][(it * 256 + (tid & 192)) * 8]);
    }
  };
  stageEj(0, 0);
  __syncthreads();
  bf16x8_t afrag[2];
  #pragma unroll
  for (int s2i = 0; s2i < 2; ++s2i)
    afrag[s2i] = *(const bf16x8_t*)&Ei[(wid * 16 + (lane & 15)) * 64 + s2i * 32 + (lane >> 4) * 8];
  int rloc = wid * 16 + ((lane >> 4) << 2);
  float sqi[4];
  #pragma unroll
  for (int r = 0; r < 4; ++r) sqi[r] = sq[b * NN + i0 + rloc + r];
  float rs[4] = {0.f, 0.f, 0.f, 0.f};

  for (int jt = 0; jt < NN / 128; ++jt) {
    int cur = jt & 1;
    if (jt + 1 < NN / 128) stageEj(cur ^ 1, (jt + 1) * 128);
    int j0 = jt * 128;
    #pragma unroll
    for (int n = 0; n < 8; ++n) {
      f32x4_t g = {0.f, 0.f, 0.f, 0.f};
      #pragma unroll
      for (int s2i = 0; s2i < 2; ++s2i) {
        bf16x8_t bfr = *(const bf16x8_t*)&Ej[cur][(n * 16 + (lane & 15)) * 64 + s2i * 32 + (lane >> 4) * 8];
        g = __builtin_amdgcn_mfma_f32_16x16x32_bf16(afrag[s2i], bfr, g, 0, 0, 0);
      }
      int col = j0 + n * 16 + (lane & 15);
      float sqj = sq[b * NN + col];
      #pragma unroll
      for (int r = 0; r < 4; ++r) {
        float d2 = sqi[r] + sqj - 2.0f * g[r];
        d2 = fmaxf(d2, 0.0f);
        float w = __expf(-d2);
        unsigned short wb = f2bf(w);
        rs[r] += bf2f(wb);
        wout[(long)b * NN * NN + (long)(i0 + rloc + r) * NN + col] = wb;
      }
    }
    __syncthreads();
  }
  #pragma unroll
  for (int off = 1; off < 16; off <<= 1) {
    #pragma unroll
    for (int r = 0; r < 4; ++r) rs[r] += __shfl_xor(rs[r], off);
  }
  if ((lane & 15) == 0) {
    #pragma unroll
    for (int r = 0; r < 4; ++r) invrs[b * NN + i0 + rloc + r] = 1.0f / rs[r];
  }
}

// ---- 128x128 MFMA GEMM, prefetch double-buffered (T3-minimum 2-phase) --------
// C = A[M,K] @ BT[N,K]^T
// EPI 0: f32 out, scale row by invrs (PV).  EPI 1: bf16 out, bias+exact GELU.
// EPI 2: f32 out, bias + residual add.
template <int EPI>
__global__ __launch_bounds__(256, 2) void gemm128(
    const unsigned short* __restrict__ A, const unsigned short* __restrict__ BT,
    void* __restrict__ Cout, const float* __restrict__ bias,
    const float* __restrict__ resid, const float* __restrict__ invrs,
    int M, int Nmat, int K, long sA, long sB, long sC, long sR) {
  __shared__ unsigned short As[2][128 * 64];
  __shared__ unsigned short Bs[2][128 * 64];
  int tid = threadIdx.x, lane = tid & 63;
  int bj = blockIdx.x, bi = blockIdx.y, bb = blockIdx.z;
  const unsigned short* Ab = A + (long)bb * sA;
  const unsigned short* Bb = BT + (long)bb * sB;
  int row0 = bi * 128, col0 = bj * 128;
  int wid = tid >> 6, wr = wid >> 1, wc = wid & 1;
  const f32x4_t fzero = {0.f, 0.f, 0.f, 0.f};
  f32x4_t acc[4][4];
  #pragma unroll
  for (int m = 0; m < 4; ++m)
    #pragma unroll
    for (int n = 0; n < 4; ++n) acc[m][n] = fzero;

  auto stage = [&](int buf, int k0) {
    #pragma unroll
    for (int it = 0; it < 4; ++it) {
      int c = it * 256 + tid;
      int r = c >> 3, c8 = c & 7;
      gload16(Ab + (long)(row0 + r) * K + k0 + c8 * 8, &As[buf][(it * 256 + (tid & 192)) * 8]);
      int rr = col0 + r;
      if (rr >= Nmat) rr = Nmat - 1;  // N=64 tail: read valid garbage, masked on store
      gload16(Bb + (long)rr * K + k0 + c8 * 8, &Bs[buf][(it * 256 + (tid & 192)) * 8]);
    }
  };

  stage(0, 0);
  __syncthreads();   // drains vmcnt(0): buf0 ready

  int nk = K >> 6;
  for (int t = 0; t < nk; ++t) {
    int cur = t & 1;
    if (t + 1 < nk) stage(cur ^ 1, (t + 1) << 6);  // loads in flight across MFMA phase
    #pragma unroll
    for (int s2i = 0; s2i < 2; ++s2i) {
      bf16x8_t a[4], bfr[4];
      int lr = lane & 15, lk = s2i * 32 + (lane >> 4) * 8;
      #pragma unroll
      for (int m = 0; m < 4; ++m)
        a[m] = *(const bf16x8_t*)&As[cur][(wr * 64 + m * 16 + lr) * 64 + lk];
      #pragma unroll
      for (int n = 0; n < 4; ++n)
        bfr[n] = *(const bf16x8_t*)&Bs[cur][(wc * 64 + n * 16 + lr) * 64 + lk];
      #pragma unroll
      for (int m = 0; m < 4; ++m)
        #pragma unroll
        for (int n = 0; n < 4; ++n)
          acc[m][n] = __builtin_amdgcn_mfma_f32_16x16x32_bf16(a[m], bfr[n], acc[m][n], 0, 0, 0);
    }
    __syncthreads();  // drains vmcnt(0)+lgkmcnt(0); next buffer ready, this one reusable
  }

  int rbase = row0 + wr * 64 + ((lane >> 4) << 2);
  int cbase = col0 + wc * 64 + (lane & 15);
  #pragma unroll
  for (int n = 0; n < 4; ++n) {
    int col = cbase + n * 16;
    if (col >= Nmat) continue;
    float bv = (EPI != 0) ? bias[col] : 0.f;
    #pragma unroll
    for (int m = 0; m < 4; ++m) {
      #pragma unroll
      for (int r = 0; r < 4; ++r) {
        int row = rbase + m * 16 + r;
        float v = acc[m][n][r];
        long cidx = (long)bb * sC + (long)row * Nmat + col;
        if (EPI == 0) {
          v *= invrs[(long)bb * sR + row];
          ((float*)Cout)[cidx] = v;
        } else if (EPI == 1) {
          ((unsigned short*)Cout)[cidx] = f2bf(gelu_fast(v + bv));
        } else {
          v += bv + resid[(long)bb * sR + (long)row * Nmat + col];
          ((float*)Cout)[cidx] = v;
        }
      }
    }
  }
}

extern "C" void kernel_launch(void* const* d_in, const int* in_sizes, int n_in,
                              void* d_out, int out_size, void* d_ws, size_t ws_size,
                              hipStream_t stream) {
  (void)in_sizes; (void)n_in; (void)out_size; (void)ws_size;
  const float* in_z   = (const float*)d_in[0];
  const float* in_s   = (const float*)d_in[1];
  const float* lnz_sc = (const float*)d_in[2];
  const float* lnz_bi = (const float*)d_in[3];
  const float* lns_sc = (const float*)d_in[4];
  const float* lns_bi = (const float*)d_in[5];
  const float* Wz1 = (const float*)d_in[6];
  const float* bz1 = (const float*)d_in[7];
  const float* Wz2 = (const float*)d_in[8];
  const float* bz2 = (const float*)d_in[9];
  const float* Ws1 = (const float*)d_in[10];
  const float* bs1 = (const float*)d_in[11];
  const float* Ws2 = (const float*)d_in[12];
  const float* bs2 = (const float*)d_in[13];
  float* out_z = (float*)d_out;
  float* out_s = out_z + (long)ROWS * ZDIM;

  // workspace layout (~200.4 MB)
  char* ws = (char*)d_ws;
  size_t off = 0;
  auto alloc = [&](size_t bytes) { void* p = ws + off; off += (bytes + 255) & ~(size_t)255; return p; };
  unsigned short* WH   = (unsigned short*)alloc((size_t)BATCH * NN * NN * 2); // w / h aliased (67MB)
  unsigned short* ZT   = (unsigned short*)alloc((size_t)BATCH * ZDIM * NN * 2);
  unsigned short* XLN  = (unsigned short*)alloc((size_t)ROWS * ZDIM * 2);
  unsigned short* EBF  = (unsigned short*)alloc((size_t)ROWS * SDIM * 2);
  float* ZATT = (float*)alloc((size_t)ROWS * ZDIM * 4);
  float* ZBUF = (float*)alloc((size_t)ROWS * ZDIM * 4);
  float* SBUF = (float*)alloc((size_t)ROWS * SDIM * 4);
  float* SQ   = (float*)alloc((size_t)ROWS * 4);
  float* IRS  = (float*)alloc((size_t)ROWS * 4);
  unsigned short* W1Z = (unsigned short*)alloc((size_t)DEPTH * MLPD * ZDIM * 2);
  unsigned short* W2Z = (unsigned short*)alloc((size_t)DEPTH * ZDIM * MLPD * 2);
  unsigned short* W1S = (unsigned short*)alloc((size_t)DEPTH * MLPD * ZDIM * 2);
  unsigned short* W2S = (unsigned short*)alloc((size_t)DEPTH * SDIM * MLPD * 2);

  // weight transpose+convert (B^T layout [N][K] for MFMA B-operand)
  tconv_kernel<<<dim3(MLPD / 32, ZDIM / 32, DEPTH), dim3(32, 8), 0, stream>>>(
      Wz1, W1Z, ZDIM, MLPD, (long)ZDIM * MLPD, (long)MLPD * ZDIM);
  tconv_kernel<<<dim3(ZDIM / 32, MLPD / 32, DEPTH), dim3(32, 8), 0, stream>>>(
      Wz2, W2Z, MLPD, ZDIM, (long)MLPD * ZDIM, (long)ZDIM * MLPD);
  tconv_kernel<<<dim3(MLPD / 32, ZDIM / 32, DEPTH), dim3(32, 8), 0, stream>>>(
      Ws1, W1S, ZDIM, MLPD, (long)ZDIM * MLPD, (long)MLPD * ZDIM);
  tconv_kernel<<<dim3(SDIM / 32, MLPD / 32, DEPTH), dim3(32, 8), 0, stream>>>(
      Ws2, W2S, MLPD, SDIM, (long)MLPD * SDIM, (long)SDIM * MLPD);

  for (int L = 0; L < DEPTH; ++L) {
    const float* z_in = (L == 0) ? in_z : ZBUF;
    const float* s_in = (L == 0) ? in_s : SBUF;
    float* z_out = (L == DEPTH - 1) ? out_z : ZBUF;
    float* s_out = (L == DEPTH - 1) ? out_s : SBUF;

    conv_e_kernel<<<ROWS / 4, 256, 0, stream>>>(s_in, EBF, SQ);
    tconv_kernel<<<dim3(ZDIM / 32, NN / 32, BATCH), dim3(32, 8), 0, stream>>>(
        z_in, ZT, NN, ZDIM, (long)NN * ZDIM, (long)ZDIM * NN);
    attn_w_kernel<<<dim3(NN / 64, BATCH), 256, 0, stream>>>(EBF, SQ, WH, IRS);
    // z_att = (w @ z) / rowsum
    gemm128<0><<<dim3(ZDIM / 128, NN / 128, BATCH), 256, 0, stream>>>(
        WH, ZT, ZATT, nullptr, nullptr, IRS,
        NN, ZDIM, NN, (long)NN * NN, (long)ZDIM * NN, (long)NN * ZDIM, NN);
    // z-FF
    ln_kernel<<<ROWS / 4, 256, 0, stream>>>(ZATT, lnz_sc + L * ZDIM, lnz_bi + L * ZDIM, XLN);
    gemm128<1><<<dim3(MLPD / 128, ROWS / 128, 1), 256, 0, stream>>>(
        XLN, W1Z + (long)L * MLPD * ZDIM, WH, bz1 + L * MLPD, nullptr, nullptr,
        ROWS, MLPD, ZDIM, 0, 0, 0, 0);
    gemm128<2><<<dim3(ZDIM / 128, ROWS / 128, 1), 256, 0, stream>>>(
        WH, W2Z + (long)L * ZDIM * MLPD, z_out, bz2 + L * ZDIM, ZATT, nullptr,
        ROWS, ZDIM, MLPD, 0, 0, 0, 0);
    // s-FF
    ln_kernel<<<ROWS / 4, 256, 0, stream>>>(z_out, lns_sc + L * ZDIM, lns_bi + L * ZDIM, XLN);
    gemm128<1><<<dim3(MLPD / 128, ROWS / 128, 1), 256, 0, stream>>>(
        XLN, W1S + (long)L * MLPD * ZDIM, WH, bs1 + L * MLPD, nullptr, nullptr,
        ROWS, MLPD, ZDIM, 0, 0, 0, 0);
    gemm128<2><<<dim3(1, ROWS / 128, 1), 256, 0, stream>>>(
        WH, W2S + (long)L * SDIM * MLPD, s_out, bs2 + L * SDIM, s_in, nullptr,
        ROWS, SDIM, MLPD, 0, 0, 0, 0);
  }
}

// Round 3
// 1480.690 us; speedup vs baseline: 1.0249x; 1.0051x over previous
//
#include <hip/hip_runtime.h>
#include <stdint.h>

#define DEPTH 4
#define BATCH 8
#define NN 2048
#define ZDIM 512
#define SDIM 64
#define MLPD 2048
#define ROWS (BATCH*NN)   // 16384

typedef __bf16 bf16x8_t __attribute__((ext_vector_type(8)));
typedef float f32x4_t __attribute__((ext_vector_type(4)));

#define AS1 __attribute__((address_space(1)))
#define AS3 __attribute__((address_space(3)))
typedef AS3 unsigned short* lds_us_p;

__device__ __forceinline__ void gload16(const void* g, void* l) {
  __builtin_amdgcn_global_load_lds((const AS1 void*)g, (AS3 void*)l, 16, 0, 0);
}
__device__ __forceinline__ void gload16_l(const void* g, lds_us_p l) {
  __builtin_amdgcn_global_load_lds((const AS1 void*)g, (AS3 void*)l, 16, 0, 0);
}

__device__ __forceinline__ unsigned short f2bf(float f) {
  union { float f; unsigned u; } v; v.f = f;
  unsigned u = v.u;
  unsigned r = (u + 0x7fffu + ((u >> 16) & 1u)) >> 16;
  return (unsigned short)r;
}
__device__ __forceinline__ float bf2f(unsigned short h) {
  union { unsigned u; float f; } v; v.u = ((unsigned)h) << 16;
  return v.f;
}

// exact-erf GELU via Abramowitz-Stegun 7.1.26 (max abs err 1.5e-7)
__device__ __forceinline__ float gelu_fast(float x) {
  float ax = fabsf(x) * 0.70710678118654752440f;
  float t = __builtin_amdgcn_rcpf(1.0f + 0.3275911f * ax);
  float p = t * (0.254829592f + t * (-0.284496736f + t * (1.421413741f +
            t * (-1.453152027f + t * 1.061405429f))));
  float er = 1.0f - p * __expf(-ax * ax);
  float s = (x >= 0.f) ? er : -er;
  return 0.5f * x * (1.0f + s);
}

// ---- convert spatial embedding rows to bf16 + squared norms ------------------
__global__ __launch_bounds__(256) void conv_e_kernel(const float* __restrict__ s,
    unsigned short* __restrict__ ebf, float* __restrict__ sq) {
  int lane = threadIdx.x & 63;
  int row = blockIdx.x * 4 + (threadIdx.x >> 6);
  float x = s[(long)row * SDIM + lane];
  unsigned short v = f2bf(x);
  ebf[(long)row * SDIM + lane] = v;
  float xb = bf2f(v);
  float ss = xb * xb;
  #pragma unroll
  for (int off = 32; off > 0; off >>= 1) ss += __shfl_xor(ss, off);
  if (lane == 0) sq[row] = ss;
}

// ---- transpose + f32->bf16: in [R][C] f32 -> out [C][R] bf16, batched --------
__global__ __launch_bounds__(256) void tconv_kernel(const float* __restrict__ in,
    unsigned short* __restrict__ out, int R, int C, long sIn, long sOut) {
  __shared__ float tile[32][33];
  int b = blockIdx.z;
  int c0 = blockIdx.x * 32, r0 = blockIdx.y * 32;
  int tx = threadIdx.x, ty = threadIdx.y;
  const float* ib = in + (long)b * sIn;
  unsigned short* ob = out + (long)b * sOut;
  #pragma unroll
  for (int i = 0; i < 32; i += 8)
    tile[ty + i][tx] = ib[(long)(r0 + ty + i) * C + c0 + tx];
  __syncthreads();
  #pragma unroll
  for (int i = 0; i < 32; i += 8)
    ob[(long)(c0 + ty + i) * R + r0 + tx] = f2bf(tile[tx][ty + i]);
}

// ---- LayerNorm over D=512, write bf16 normalized rows ------------------------
__global__ __launch_bounds__(256) void ln_kernel(const float* __restrict__ x,
    const float* __restrict__ scale, const float* __restrict__ bias,
    unsigned short* __restrict__ y) {
  int lane = threadIdx.x & 63;
  long row = (long)blockIdx.x * 4 + (threadIdx.x >> 6);
  const float* xr = x + row * ZDIM + lane * 8;
  float4 v0 = *(const float4*)xr;
  float4 v1 = *(const float4*)(xr + 4);
  float xv[8] = {v0.x, v0.y, v0.z, v0.w, v1.x, v1.y, v1.z, v1.w};
  float s1 = 0.f, s2 = 0.f;
  #pragma unroll
  for (int k = 0; k < 8; ++k) { s1 += xv[k]; s2 += xv[k] * xv[k]; }
  #pragma unroll
  for (int off = 32; off > 0; off >>= 1) {
    s1 += __shfl_xor(s1, off);
    s2 += __shfl_xor(s2, off);
  }
  float mean = s1 * (1.0f / ZDIM);
  float var = s2 * (1.0f / ZDIM) - mean * mean;
  float rstd = rsqrtf(var + 1e-5f);
  const float* sc = scale + lane * 8;
  const float* bi = bias + lane * 8;
  alignas(16) unsigned short o[8];
  #pragma unroll
  for (int k = 0; k < 8; ++k)
    o[k] = f2bf((xv[k] - mean) * rstd * sc[k] + bi[k]);
  *(uint4*)(y + row * ZDIM + lane * 8) = *(const uint4*)o;
}

// ---- attention weights: w = exp(-max(sq_i+sq_j-2*e_i.e_j,0)), plus 1/rowsum --
__global__ __launch_bounds__(256) void attn_w_kernel(const unsigned short* __restrict__ ebf,
    const float* __restrict__ sq, unsigned short* __restrict__ wout,
    float* __restrict__ invrs) {
  __shared__ unsigned short Ei[64 * 64];
  __shared__ unsigned short Ej[2][128 * 64];
  int tid = threadIdx.x, lane = tid & 63, wid = tid >> 6;
  int b = blockIdx.y;
  int i0 = blockIdx.x * 64;
  const unsigned short* eb = ebf + (long)b * NN * SDIM;

  #pragma unroll
  for (int it = 0; it < 2; ++it) {
    int c = it * 256 + tid;
    int r = c >> 3, c8 = c & 7;
    gload16(eb + (long)(i0 + r) * SDIM + c8 * 8, Ei + (it * 256 + (tid & 192)) * 8);
  }
  auto stageEj = [&](int buf, int j0) {
    #pragma unroll
    for (int it = 0; it < 4; ++it) {
      int c = it * 256 + tid;
      int r = c >> 3, c8 = c & 7;
      gload16(eb + (long)(j0 + r) * SDIM + c8 * 8, &Ej[buf][(it * 256 + (tid & 192)) * 8]);
    }
  };
  stageEj(0, 0);
  __syncthreads();
  bf16x8_t afrag[2];
  #pragma unroll
  for (int s2i = 0; s2i < 2; ++s2i)
    afrag[s2i] = *(const bf16x8_t*)&Ei[(wid * 16 + (lane & 15)) * 64 + s2i * 32 + (lane >> 4) * 8];
  int rloc = wid * 16 + ((lane >> 4) << 2);
  float sqi[4];
  #pragma unroll
  for (int r = 0; r < 4; ++r) sqi[r] = sq[b * NN + i0 + rloc + r];
  float rs[4] = {0.f, 0.f, 0.f, 0.f};

  for (int jt = 0; jt < NN / 128; ++jt) {
    int cur = jt & 1;
    if (jt + 1 < NN / 128) stageEj(cur ^ 1, (jt + 1) * 128);
    int j0 = jt * 128;
    #pragma unroll
    for (int n = 0; n < 8; ++n) {
      f32x4_t g = {0.f, 0.f, 0.f, 0.f};
      #pragma unroll
      for (int s2i = 0; s2i < 2; ++s2i) {
        bf16x8_t bfr = *(const bf16x8_t*)&Ej[cur][(n * 16 + (lane & 15)) * 64 + s2i * 32 + (lane >> 4) * 8];
        g = __builtin_amdgcn_mfma_f32_16x16x32_bf16(afrag[s2i], bfr, g, 0, 0, 0);
      }
      int col = j0 + n * 16 + (lane & 15);
      float sqj = sq[b * NN + col];
      #pragma unroll
      for (int r = 0; r < 4; ++r) {
        float d2 = sqi[r] + sqj - 2.0f * g[r];
        d2 = fmaxf(d2, 0.0f);
        float w = __expf(-d2);
        unsigned short wb = f2bf(w);
        rs[r] += bf2f(wb);
        wout[(long)b * NN * NN + (long)(i0 + rloc + r) * NN + col] = wb;
      }
    }
    __syncthreads();
  }
  #pragma unroll
  for (int off = 1; off < 16; off <<= 1) {
    #pragma unroll
    for (int r = 0; r < 4; ++r) rs[r] += __shfl_xor(rs[r], off);
  }
  if ((lane & 15) == 0) {
    #pragma unroll
    for (int r = 0; r < 4; ++r) invrs[b * NN + i0 + rloc + r] = 1.0f / rs[r];
  }
}

// ==== gemm256: BM=128, BN=256, BK=64, 512 thr (8 waves 2Mx4N, 64x64/wave) =====
// 3-buffer LDS pipeline, counted vmcnt (never 0 in loop), T2 content-swizzle
// (source-swizzled global_load_lds + swizzled ds_read: chunk ^= row&7).
// C = A[M,K] @ BT[N,K]^T. Full tiles assumed (M%128==0, N%256==0, K%64==0).
// EPI 0: f32 out, row-scale invrs.  EPI 1: bf16 out, bias+GELU.  EPI 2: f32,
// bias + residual.
template <int EPI>
__global__ __launch_bounds__(512, 2) void gemm256(
    const unsigned short* __restrict__ A, const unsigned short* __restrict__ BT,
    void* __restrict__ Cout, const float* __restrict__ bias,
    const float* __restrict__ resid, const float* __restrict__ invrs,
    int Nmat, int K, long sA, long sB, long sC, long sR) {
  __shared__ unsigned short AsBuf[3][128 * 64];
  __shared__ unsigned short BsBuf[3][256 * 64];
  int tid = threadIdx.x, lane = tid & 63;
  int lr = lane & 15, hi = lane >> 4;
  int wbase = tid & 448;
  int bj = blockIdx.x, bi = blockIdx.y, bb = blockIdx.z;
  const unsigned short* Ab = A + (long)bb * sA;
  const unsigned short* Bb = BT + (long)bb * sB;
  int row0 = bi * 128, col0 = bj * 256;
  int wid = tid >> 6, wr = wid >> 2, wc = wid & 3;

  // per-thread swizzled global source pointers (advance 64 elem per K-step)
  const unsigned short* pA[2];
  const unsigned short* pB[4];
  #pragma unroll
  for (int it = 0; it < 2; ++it) {
    int g = it * 512 + tid, r = g >> 3, c = g & 7;
    pA[it] = Ab + (long)(row0 + r) * K + ((c ^ (r & 7)) * 8);
  }
  #pragma unroll
  for (int it = 0; it < 4; ++it) {
    int g = it * 512 + tid, r = g >> 3, c = g & 7;
    pB[it] = Bb + (long)(col0 + r) * K + ((c ^ (r & 7)) * 8);
  }
  // LDS fragment offsets (elements), swizzle-matched; compile-time unrolled
  int offA[4][2], offB[4][2];
  #pragma unroll
  for (int m = 0; m < 4; ++m) {
    #pragma unroll
    for (int s = 0; s < 2; ++s) {
      int ra = wr * 64 + m * 16 + lr;
      offA[m][s] = ra * 64 + (((s * 4 + hi) ^ (ra & 7)) * 8);
      int rb = wc * 64 + m * 16 + lr;
      offB[m][s] = rb * 64 + (((s * 4 + hi) ^ (rb & 7)) * 8);
    }
  }

  lds_us_p A0 = (lds_us_p)&AsBuf[0][0], A1 = (lds_us_p)&AsBuf[1][0], A2 = (lds_us_p)&AsBuf[2][0];
  lds_us_p B0 = (lds_us_p)&BsBuf[0][0], B1 = (lds_us_p)&BsBuf[1][0], B2 = (lds_us_p)&BsBuf[2][0];

  auto stage = [&](lds_us_p dA, lds_us_p dB) {
    #pragma unroll
    for (int it = 0; it < 2; ++it) {
      gload16_l(pA[it], dA + (it * 512 + wbase) * 8);
      pA[it] += 64;
    }
    #pragma unroll
    for (int it = 0; it < 4; ++it) {
      gload16_l(pB[it], dB + (it * 512 + wbase) * 8);
      pB[it] += 64;
    }
  };

  const f32x4_t fzero = {0.f, 0.f, 0.f, 0.f};
  f32x4_t acc[4][4];
  #pragma unroll
  for (int m = 0; m < 4; ++m)
    #pragma unroll
    for (int n = 0; n < 4; ++n) acc[m][n] = fzero;

  int nk = K >> 6;
  stage(A0, B0);   // tile 0
  stage(A1, B1);   // tile 1: 12 loads/wave outstanding

  for (int t = 0; t < nk; ++t) {
    // wait: tile t's 6 loads (oldest) landed; own ds_reads of t-1 fully done.
    if (t + 1 < nk) asm volatile("s_waitcnt vmcnt(6) lgkmcnt(0)" ::: "memory");
    else            asm volatile("s_waitcnt vmcnt(0) lgkmcnt(0)" ::: "memory");
    __builtin_amdgcn_s_barrier();
    __builtin_amdgcn_sched_barrier(0);
    if (t + 2 < nk) stage(A2, B2);  // overwrites buffer read in iter t-1 (safe)
    #pragma unroll
    for (int s = 0; s < 2; ++s) {
      bf16x8_t a[4], b[4];
      #pragma unroll
      for (int m = 0; m < 4; ++m) a[m] = *(const AS3 bf16x8_t*)(A0 + offA[m][s]);
      #pragma unroll
      for (int n = 0; n < 4; ++n) b[n] = *(const AS3 bf16x8_t*)(B0 + offB[n][s]);
      #pragma unroll
      for (int m = 0; m < 4; ++m)
        #pragma unroll
        for (int n = 0; n < 4; ++n)
          acc[m][n] = __builtin_amdgcn_mfma_f32_16x16x32_bf16(a[m], b[n], acc[m][n], 0, 0, 0);
    }
    lds_us_p tA = A0; A0 = A1; A1 = A2; A2 = tA;
    lds_us_p tB = B0; B0 = B1; B1 = B2; B2 = tB;
  }

  // epilogue
  int rbase = row0 + wr * 64 + hi * 4;
  int cbase = col0 + wc * 64 + lr;
  float bv[4];
  #pragma unroll
  for (int n = 0; n < 4; ++n) bv[n] = (EPI != 0) ? bias[cbase + n * 16] : 0.f;
  #pragma unroll
  for (int m = 0; m < 4; ++m) {
    #pragma unroll
    for (int r = 0; r < 4; ++r) {
      int row = rbase + m * 16 + r;
      float ir = (EPI == 0) ? invrs[(long)bb * sR + row] : 0.f;
      #pragma unroll
      for (int n = 0; n < 4; ++n) {
        int col = cbase + n * 16;
        float v = acc[m][n][r];
        long cidx = (long)bb * sC + (long)row * Nmat + col;
        if (EPI == 0) {
          ((float*)Cout)[cidx] = v * ir;
        } else if (EPI == 1) {
          ((unsigned short*)Cout)[cidx] = f2bf(gelu_fast(v + bv[n]));
        } else {
          ((float*)Cout)[cidx] = v + bv[n] + resid[(long)bb * sR + (long)row * Nmat + col];
        }
      }
    }
  }
}

// ---- old 128x128 GEMM kept only for the N=64 s-FF2 tail ----------------------
template <int EPI>
__global__ __launch_bounds__(256, 2) void gemm128(
    const unsigned short* __restrict__ A, const unsigned short* __restrict__ BT,
    void* __restrict__ Cout, const float* __restrict__ bias,
    const float* __restrict__ resid, const float* __restrict__ invrs,
    int M, int Nmat, int K, long sA, long sB, long sC, long sR) {
  __shared__ unsigned short As[2][128 * 64];
  __shared__ unsigned short Bs[2][128 * 64];
  int tid = threadIdx.x, lane = tid & 63;
  int bj = blockIdx.x, bi = blockIdx.y, bb = blockIdx.z;
  const unsigned short* Ab = A + (long)bb * sA;
  const unsigned short* Bb = BT + (long)bb * sB;
  int row0 = bi * 128, col0 = bj * 128;
  int wid = tid >> 6, wr = wid >> 1, wc = wid & 1;
  const f32x4_t fzero = {0.f, 0.f, 0.f, 0.f};
  f32x4_t acc[4][4];
  #pragma unroll
  for (int m = 0; m < 4; ++m)
    #pragma unroll
    for (int n = 0; n < 4; ++n) acc[m][n] = fzero;

  auto stage = [&](int buf, int k0) {
    #pragma unroll
    for (int it = 0; it < 4; ++it) {
      int c = it * 256 + tid;
      int r = c >> 3, c8 = c & 7;
      gload16(Ab + (long)(row0 + r) * K + k0 + c8 * 8, &As[buf][(it * 256 + (tid & 192)) * 8]);
      int rr = col0 + r;
      if (rr >= Nmat) rr = Nmat - 1;
      gload16(Bb + (long)rr * K + k0 + c8 * 8, &Bs[buf][(it * 256 + (tid & 192)) * 8]);
    }
  };

  stage(0, 0);
  __syncthreads();

  int nk = K >> 6;
  for (int t = 0; t < nk; ++t) {
    int cur = t & 1;
    if (t + 1 < nk) stage(cur ^ 1, (t + 1) << 6);
    #pragma unroll
    for (int s2i = 0; s2i < 2; ++s2i) {
      bf16x8_t a[4], bfr[4];
      int lr = lane & 15, lk = s2i * 32 + (lane >> 4) * 8;
      #pragma unroll
      for (int m = 0; m < 4; ++m)
        a[m] = *(const bf16x8_t*)&As[cur][(wr * 64 + m * 16 + lr) * 64 + lk];
      #pragma unroll
      for (int n = 0; n < 4; ++n)
        bfr[n] = *(const bf16x8_t*)&Bs[cur][(wc * 64 + n * 16 + lr) * 64 + lk];
      #pragma unroll
      for (int m = 0; m < 4; ++m)
        #pragma unroll
        for (int n = 0; n < 4; ++n)
          acc[m][n] = __builtin_amdgcn_mfma_f32_16x16x32_bf16(a[m], bfr[n], acc[m][n], 0, 0, 0);
    }
    __syncthreads();
  }

  int rbase = row0 + wr * 64 + ((lane >> 4) << 2);
  int cbase = col0 + wc * 64 + (lane & 15);
  #pragma unroll
  for (int n = 0; n < 4; ++n) {
    int col = cbase + n * 16;
    if (col >= Nmat) continue;
    float bvv = (EPI != 0) ? bias[col] : 0.f;
    #pragma unroll
    for (int m = 0; m < 4; ++m) {
      #pragma unroll
      for (int r = 0; r < 4; ++r) {
        int row = rbase + m * 16 + r;
        float v = acc[m][n][r];
        long cidx = (long)bb * sC + (long)row * Nmat + col;
        if (EPI == 0) {
          v *= invrs[(long)bb * sR + row];
          ((float*)Cout)[cidx] = v;
        } else if (EPI == 1) {
          ((unsigned short*)Cout)[cidx] = f2bf(gelu_fast(v + bvv));
        } else {
          v += bvv + resid[(long)bb * sR + (long)row * Nmat + col];
          ((float*)Cout)[cidx] = v;
        }
      }
    }
  }
}

extern "C" void kernel_launch(void* const* d_in, const int* in_sizes, int n_in,
                              void* d_out, int out_size, void* d_ws, size_t ws_size,
                              hipStream_t stream) {
  (void)in_sizes; (void)n_in; (void)out_size; (void)ws_size;
  const float* in_z   = (const float*)d_in[0];
  const float* in_s   = (const float*)d_in[1];
  const float* lnz_sc = (const float*)d_in[2];
  const float* lnz_bi = (const float*)d_in[3];
  const float* lns_sc = (const float*)d_in[4];
  const float* lns_bi = (const float*)d_in[5];
  const float* Wz1 = (const float*)d_in[6];
  const float* bz1 = (const float*)d_in[7];
  const float* Wz2 = (const float*)d_in[8];
  const float* bz2 = (const float*)d_in[9];
  const float* Ws1 = (const float*)d_in[10];
  const float* bs1 = (const float*)d_in[11];
  const float* Ws2 = (const float*)d_in[12];
  const float* bs2 = (const float*)d_in[13];
  float* out_z = (float*)d_out;
  float* out_s = out_z + (long)ROWS * ZDIM;

  char* ws = (char*)d_ws;
  size_t off = 0;
  auto alloc = [&](size_t bytes) { void* p = ws + off; off += (bytes + 255) & ~(size_t)255; return p; };
  unsigned short* WH   = (unsigned short*)alloc((size_t)BATCH * NN * NN * 2); // w / h aliased
  unsigned short* ZT   = (unsigned short*)alloc((size_t)BATCH * ZDIM * NN * 2);
  unsigned short* XLN  = (unsigned short*)alloc((size_t)ROWS * ZDIM * 2);
  unsigned short* EBF  = (unsigned short*)alloc((size_t)ROWS * SDIM * 2);
  float* ZATT = (float*)alloc((size_t)ROWS * ZDIM * 4);
  float* ZBUF = (float*)alloc((size_t)ROWS * ZDIM * 4);
  float* SBUF = (float*)alloc((size_t)ROWS * SDIM * 4);
  float* SQ   = (float*)alloc((size_t)ROWS * 4);
  float* IRS  = (float*)alloc((size_t)ROWS * 4);
  unsigned short* W1Z = (unsigned short*)alloc((size_t)DEPTH * MLPD * ZDIM * 2);
  unsigned short* W2Z = (unsigned short*)alloc((size_t)DEPTH * ZDIM * MLPD * 2);
  unsigned short* W1S = (unsigned short*)alloc((size_t)DEPTH * MLPD * ZDIM * 2);
  unsigned short* W2S = (unsigned short*)alloc((size_t)DEPTH * SDIM * MLPD * 2);

  tconv_kernel<<<dim3(MLPD / 32, ZDIM / 32, DEPTH), dim3(32, 8), 0, stream>>>(
      Wz1, W1Z, ZDIM, MLPD, (long)ZDIM * MLPD, (long)MLPD * ZDIM);
  tconv_kernel<<<dim3(ZDIM / 32, MLPD / 32, DEPTH), dim3(32, 8), 0, stream>>>(
      Wz2, W2Z, MLPD, ZDIM, (long)MLPD * ZDIM, (long)ZDIM * MLPD);
  tconv_kernel<<<dim3(MLPD / 32, ZDIM / 32, DEPTH), dim3(32, 8), 0, stream>>>(
      Ws1, W1S, ZDIM, MLPD, (long)ZDIM * MLPD, (long)MLPD * ZDIM);
  tconv_kernel<<<dim3(SDIM / 32, MLPD / 32, DEPTH), dim3(32, 8), 0, stream>>>(
      Ws2, W2S, MLPD, SDIM, (long)MLPD * SDIM, (long)SDIM * MLPD);

  for (int L = 0; L < DEPTH; ++L) {
    const float* z_in = (L == 0) ? in_z : ZBUF;
    const float* s_in = (L == 0) ? in_s : SBUF;
    float* z_out = (L == DEPTH - 1) ? out_z : ZBUF;
    float* s_out = (L == DEPTH - 1) ? out_s : SBUF;

    conv_e_kernel<<<ROWS / 4, 256, 0, stream>>>(s_in, EBF, SQ);
    tconv_kernel<<<dim3(ZDIM / 32, NN / 32, BATCH), dim3(32, 8), 0, stream>>>(
        z_in, ZT, NN, ZDIM, (long)NN * ZDIM, (long)ZDIM * NN);
    attn_w_kernel<<<dim3(NN / 64, BATCH), 256, 0, stream>>>(EBF, SQ, WH, IRS);
    // z_att = (w @ z) / rowsum : M=NN, N=ZDIM, K=NN, batched
    gemm256<0><<<dim3(ZDIM / 256, NN / 128, BATCH), 512, 0, stream>>>(
        WH, ZT, ZATT, nullptr, nullptr, IRS,
        ZDIM, NN, (long)NN * NN, (long)ZDIM * NN, (long)NN * ZDIM, NN);
    // z-FF
    ln_kernel<<<ROWS / 4, 256, 0, stream>>>(ZATT, lnz_sc + L * ZDIM, lnz_bi + L * ZDIM, XLN);
    gemm256<1><<<dim3(MLPD / 256, ROWS / 128, 1), 512, 0, stream>>>(
        XLN, W1Z + (long)L * MLPD * ZDIM, WH, bz1 + L * MLPD, nullptr, nullptr,
        MLPD, ZDIM, 0, 0, 0, 0);
    gemm256<2><<<dim3(ZDIM / 256, ROWS / 128, 1), 512, 0, stream>>>(
        WH, W2Z + (long)L * ZDIM * MLPD, z_out, bz2 + L * ZDIM, ZATT, nullptr,
        ZDIM, MLPD, 0, 0, 0, 0);
    // s-FF
    ln_kernel<<<ROWS / 4, 256, 0, stream>>>(z_out, lns_sc + L * ZDIM, lns_bi + L * ZDIM, XLN);
    gemm256<1><<<dim3(MLPD / 256, ROWS / 128, 1), 512, 0, stream>>>(
        XLN, W1S + (long)L * MLPD * ZDIM, WH, bs1 + L * MLPD, nullptr, nullptr,
        MLPD, ZDIM, 0, 0, 0, 0);
    gemm128<2><<<dim3(1, ROWS / 128, 1), 256, 0, stream>>>(
        WH, W2S + (long)L * SDIM * MLPD, s_out, bs2 + L * SDIM, s_in, nullptr,
        ROWS, SDIM, MLPD, 0, 0, 0, 0);
  }
}

// Round 4
// 1354.645 us; speedup vs baseline: 1.1202x; 1.0930x over previous
//
#include <hip/hip_runtime.h>
#include <stdint.h>

#define DEPTH 4
#define BATCH 8
#define NN 2048
#define ZDIM 512
#define SDIM 64
#define MLPD 2048
#define ROWS (BATCH*NN)   // 16384

typedef __bf16 bf16x8_t __attribute__((ext_vector_type(8)));
typedef float f32x4_t __attribute__((ext_vector_type(4)));
typedef unsigned short us;

#define AS1 __attribute__((address_space(1)))
#define AS3 __attribute__((address_space(3)))
typedef AS3 unsigned short* lds_us_p;

__device__ __forceinline__ void gload16(const void* g, void* l) {
  __builtin_amdgcn_global_load_lds((const AS1 void*)g, (AS3 void*)l, 16, 0, 0);
}
__device__ __forceinline__ void gload16_l(const void* g, lds_us_p l) {
  __builtin_amdgcn_global_load_lds((const AS1 void*)g, (AS3 void*)l, 16, 0, 0);
}

__device__ __forceinline__ unsigned short f2bf(float f) {
  union { float f; unsigned u; } v; v.f = f;
  unsigned u = v.u;
  unsigned r = (u + 0x7fffu + ((u >> 16) & 1u)) >> 16;
  return (unsigned short)r;
}
__device__ __forceinline__ float bf2f(unsigned short h) {
  union { unsigned u; float f; } v; v.u = ((unsigned)h) << 16;
  return v.f;
}

// exact-erf GELU via Abramowitz-Stegun 7.1.26 (max abs err 1.5e-7)
__device__ __forceinline__ float gelu_fast(float x) {
  float ax = fabsf(x) * 0.70710678118654752440f;
  float t = __builtin_amdgcn_rcpf(1.0f + 0.3275911f * ax);
  float p = t * (0.254829592f + t * (-0.284496736f + t * (1.421413741f +
            t * (-1.453152027f + t * 1.061405429f))));
  float er = 1.0f - p * __expf(-ax * ax);
  float s = (x >= 0.f) ? er : -er;
  return 0.5f * x * (1.0f + s);
}

// ---- convert spatial embedding rows to bf16 + squared norms ------------------
__global__ __launch_bounds__(256) void conv_e_kernel(const float* __restrict__ s,
    unsigned short* __restrict__ ebf, float* __restrict__ sq) {
  int lane = threadIdx.x & 63;
  int row = blockIdx.x * 4 + (threadIdx.x >> 6);
  float x = s[(long)row * SDIM + lane];
  unsigned short v = f2bf(x);
  ebf[(long)row * SDIM + lane] = v;
  float xb = bf2f(v);
  float ss = xb * xb;
  #pragma unroll
  for (int off = 32; off > 0; off >>= 1) ss += __shfl_xor(ss, off);
  if (lane == 0) sq[row] = ss;
}

// ---- transpose + f32->bf16: in [R][C] f32 -> out [C][R] bf16, batched --------
__global__ __launch_bounds__(256) void tconv_kernel(const float* __restrict__ in,
    unsigned short* __restrict__ out, int R, int C, long sIn, long sOut) {
  __shared__ float tile[32][33];
  int b = blockIdx.z;
  int c0 = blockIdx.x * 32, r0 = blockIdx.y * 32;
  int tx = threadIdx.x, ty = threadIdx.y;
  const float* ib = in + (long)b * sIn;
  unsigned short* ob = out + (long)b * sOut;
  #pragma unroll
  for (int i = 0; i < 32; i += 8)
    tile[ty + i][tx] = ib[(long)(r0 + ty + i) * C + c0 + tx];
  __syncthreads();
  #pragma unroll
  for (int i = 0; i < 32; i += 8)
    ob[(long)(c0 + ty + i) * R + r0 + tx] = f2bf(tile[tx][ty + i]);
}

// ---- LayerNorm over D=512, write bf16 normalized rows ------------------------
__global__ __launch_bounds__(256) void ln_kernel(const float* __restrict__ x,
    const float* __restrict__ scale, const float* __restrict__ bias,
    unsigned short* __restrict__ y) {
  int lane = threadIdx.x & 63;
  long row = (long)blockIdx.x * 4 + (threadIdx.x >> 6);
  const float* xr = x + row * ZDIM + lane * 8;
  float4 v0 = *(const float4*)xr;
  float4 v1 = *(const float4*)(xr + 4);
  float xv[8] = {v0.x, v0.y, v0.z, v0.w, v1.x, v1.y, v1.z, v1.w};
  float s1 = 0.f, s2 = 0.f;
  #pragma unroll
  for (int k = 0; k < 8; ++k) { s1 += xv[k]; s2 += xv[k] * xv[k]; }
  #pragma unroll
  for (int off = 32; off > 0; off >>= 1) {
    s1 += __shfl_xor(s1, off);
    s2 += __shfl_xor(s2, off);
  }
  float mean = s1 * (1.0f / ZDIM);
  float var = s2 * (1.0f / ZDIM) - mean * mean;
  float rstd = rsqrtf(var + 1e-5f);
  const float* sc = scale + lane * 8;
  const float* bi = bias + lane * 8;
  alignas(16) unsigned short o[8];
  #pragma unroll
  for (int k = 0; k < 8; ++k)
    o[k] = f2bf((xv[k] - mean) * rstd * sc[k] + bi[k]);
  *(uint4*)(y + row * ZDIM + lane * 8) = *(const uint4*)o;
}

// ---- attention weights: w = exp(-max(sq_i+sq_j-2*e_i.e_j,0)), plus 1/rowsum --
__global__ __launch_bounds__(256) void attn_w_kernel(const unsigned short* __restrict__ ebf,
    const float* __restrict__ sq, unsigned short* __restrict__ wout,
    float* __restrict__ invrs) {
  __shared__ unsigned short Ei[64 * 64];
  __shared__ unsigned short Ej[2][128 * 64];
  int tid = threadIdx.x, lane = tid & 63, wid = tid >> 6;
  int b = blockIdx.y;
  int i0 = blockIdx.x * 64;
  const unsigned short* eb = ebf + (long)b * NN * SDIM;

  #pragma unroll
  for (int it = 0; it < 2; ++it) {
    int c = it * 256 + tid;
    int r = c >> 3, c8 = c & 7;
    gload16(eb + (long)(i0 + r) * SDIM + c8 * 8, Ei + (it * 256 + (tid & 192)) * 8);
  }
  auto stageEj = [&](int buf, int j0) {
    #pragma unroll
    for (int it = 0; it < 4; ++it) {
      int c = it * 256 + tid;
      int r = c >> 3, c8 = c & 7;
      gload16(eb + (long)(j0 + r) * SDIM + c8 * 8, &Ej[buf][(it * 256 + (tid & 192)) * 8]);
    }
  };
  stageEj(0, 0);
  __syncthreads();
  bf16x8_t afrag[2];
  #pragma unroll
  for (int s2i = 0; s2i < 2; ++s2i)
    afrag[s2i] = *(const bf16x8_t*)&Ei[(wid * 16 + (lane & 15)) * 64 + s2i * 32 + (lane >> 4) * 8];
  int rloc = wid * 16 + ((lane >> 4) << 2);
  float sqi[4];
  #pragma unroll
  for (int r = 0; r < 4; ++r) sqi[r] = sq[b * NN + i0 + rloc + r];
  float rs[4] = {0.f, 0.f, 0.f, 0.f};

  for (int jt = 0; jt < NN / 128; ++jt) {
    int cur = jt & 1;
    if (jt + 1 < NN / 128) stageEj(cur ^ 1, (jt + 1) * 128);
    int j0 = jt * 128;
    #pragma unroll
    for (int n = 0; n < 8; ++n) {
      f32x4_t g = {0.f, 0.f, 0.f, 0.f};
      #pragma unroll
      for (int s2i = 0; s2i < 2; ++s2i) {
        bf16x8_t bfr = *(const bf16x8_t*)&Ej[cur][(n * 16 + (lane & 15)) * 64 + s2i * 32 + (lane >> 4) * 8];
        g = __builtin_amdgcn_mfma_f32_16x16x32_bf16(afrag[s2i], bfr, g, 0, 0, 0);
      }
      int col = j0 + n * 16 + (lane & 15);
      float sqj = sq[b * NN + col];
      #pragma unroll
      for (int r = 0; r < 4; ++r) {
        float d2 = sqi[r] + sqj - 2.0f * g[r];
        d2 = fmaxf(d2, 0.0f);
        float w = __expf(-d2);
        unsigned short wb = f2bf(w);
        rs[r] += bf2f(wb);
        wout[(long)b * NN * NN + (long)(i0 + rloc + r) * NN + col] = wb;
      }
    }
    __syncthreads();
  }
  #pragma unroll
  for (int off = 1; off < 16; off <<= 1) {
    #pragma unroll
    for (int r = 0; r < 4; ++r) rs[r] += __shfl_xor(rs[r], off);
  }
  if ((lane & 15) == 0) {
    #pragma unroll
    for (int r = 0; r < 4; ++r) invrs[b * NN + i0 + rloc + r] = 1.0f / rs[r];
  }
}

// ==== gemm8p: 256x256 tile, BK=64, 512 thr, 8 waves (2Mx4N), 8-phase T3+T4+T5 =
// C = A[M,K] @ BT[N,K]^T, M%256==0, N%256==0, K%128==0.
// LDS: 2 dbuf x (A[256][64] + B[256][64]) bf16, content-swizzled (chunk^=row&7).
// Per K-tile kt (dbuf d=kt&1), 4 phases (s,mh); stage schedule:
//   P1(kt): stage A-h0(kt+1)->dbuf d^1   (A dbuf d^1 freed at P4(kt-1))
//   P2(kt): stage A-h1(kt+1)->dbuf d^1
//   P3(kt): stage B-h0(kt+2)->dbuf d     (B dbuf d freed after P2: b[s1] read early)
//   P4(kt): stage B-h1(kt+2)->dbuf d ; s_waitcnt vmcnt(4) (2 newest stages in flight)
// EPI 0: f32 out, row-scale invrs.  EPI 1: bf16 out, bias+GELU.  EPI 2: f32 out,
// bias + residual.
#define MF(A_, B_, C_) __builtin_amdgcn_mfma_f32_16x16x32_bf16(A_, B_, C_, 0, 0, 0)
#define BARX() __builtin_amdgcn_s_barrier()
#define LGKM0() do { asm volatile("s_waitcnt lgkmcnt(0)" ::: "memory"); \
                     __builtin_amdgcn_sched_barrier(0); } while (0)

template <int EPI>
__global__ __launch_bounds__(512, 2) void gemm8p(
    const unsigned short* __restrict__ A, const unsigned short* __restrict__ BT,
    void* __restrict__ Cout, const float* __restrict__ bias,
    const float* __restrict__ resid, const float* __restrict__ invrs,
    int Nmat, int K, long sA, long sB, long sC, long sR) {
  __shared__ unsigned short LDSA[2][16384];   // [dbuf][256*64]
  __shared__ unsigned short LDSB[2][16384];

  int tid = threadIdx.x, lane = tid & 63;
  int lr = lane & 15, hi = lane >> 4;
  int wid = tid >> 6, wr = wid >> 2, wc = wid & 3;
  int bb = blockIdx.z;

  // bijective XCD-chunk swizzle on (x,y) linear id (all grids have nwg%8==0)
  int gx = gridDim.x;
  int wg = blockIdx.y * gx + blockIdx.x;
  int nwg = gx * gridDim.y;
  if ((nwg & 7) == 0) wg = (wg & 7) * (nwg >> 3) + (wg >> 3);
  int bj = wg % gx, bi = wg / gx;

  const unsigned short* Ab = A + (long)bb * sA;
  const unsigned short* Bb = BT + (long)bb * sB;
  int row0 = bi * 256, col0 = bj * 256;

  // ---- staging source pointers (content-swizzled), advance +64 per use ------
  int rl = tid >> 3, cc = tid & 7;
  int scs = (cc ^ (rl & 7)) * 8;
  const unsigned short* pA00 = Ab + (long)(row0 +       rl) * K + scs;
  const unsigned short* pA01 = Ab + (long)(row0 +  64 + rl) * K + scs;
  const unsigned short* pA10 = Ab + (long)(row0 + 128 + rl) * K + scs;
  const unsigned short* pA11 = Ab + (long)(row0 + 192 + rl) * K + scs;
  const unsigned short* pB00 = Bb + (long)(col0 +       rl) * K + scs;
  const unsigned short* pB01 = Bb + (long)(col0 +  64 + rl) * K + scs;
  const unsigned short* pB10 = Bb + (long)(col0 + 128 + rl) * K + scs;
  const unsigned short* pB11 = Bb + (long)(col0 + 192 + rl) * K + scs;

  lds_us_p ldsAw = (lds_us_p)&LDSA[0][0];
  lds_us_p ldsBw = (lds_us_p)&LDSB[0][0];
  int wslot = (tid & 448) * 8;   // wave-uniform chunk base * 8 elem

#define STAGE_A(DT, H) do { \
    gload16_l(pA##H##0, ldsAw + (DT)*16384 + (H)*8192 + wslot); \
    gload16_l(pA##H##1, ldsAw + (DT)*16384 + (H)*8192 + 4096 + wslot); \
    pA##H##0 += 64; pA##H##1 += 64; } while (0)
#define STAGE_B(DT, H) do { \
    gload16_l(pB##H##0, ldsBw + (DT)*16384 + (H)*8192 + wslot); \
    gload16_l(pB##H##1, ldsBw + (DT)*16384 + (H)*8192 + 4096 + wslot); \
    pB##H##0 += 64; pB##H##1 += 64; } while (0)

  // ---- ds_read fragment base pointers (swizzle-matched) ---------------------
  int key = lr & 7;
  const AS3 us* aB0 = (const AS3 us*)ldsAw + wr * 8192 + lr * 64 + ((hi ^ key) * 8);
  const AS3 us* aB1 = (const AS3 us*)ldsAw + wr * 8192 + lr * 64 + (((4 + hi) ^ key) * 8);
  const AS3 us* bB0 = (const AS3 us*)ldsBw + wc * 4096 + lr * 64 + ((hi ^ key) * 8);
  const AS3 us* bB1 = (const AS3 us*)ldsBw + wc * 4096 + lr * 64 + (((4 + hi) ^ key) * 8);

#define LDA4(BP, OFF) do { \
    a0 = *(const AS3 bf16x8_t*)((BP) + (OFF)); \
    a1 = *(const AS3 bf16x8_t*)((BP) + (OFF) + 1024); \
    a2 = *(const AS3 bf16x8_t*)((BP) + (OFF) + 2048); \
    a3 = *(const AS3 bf16x8_t*)((BP) + (OFF) + 3072); } while (0)
#define MFMA16(BASE, B0_, B1_, B2_, B3_) do { \
    acc[(BASE)+0][0]=MF(a0,B0_,acc[(BASE)+0][0]); acc[(BASE)+1][0]=MF(a1,B0_,acc[(BASE)+1][0]); \
    acc[(BASE)+2][0]=MF(a2,B0_,acc[(BASE)+2][0]); acc[(BASE)+3][0]=MF(a3,B0_,acc[(BASE)+3][0]); \
    acc[(BASE)+0][1]=MF(a0,B1_,acc[(BASE)+0][1]); acc[(BASE)+1][1]=MF(a1,B1_,acc[(BASE)+1][1]); \
    acc[(BASE)+2][1]=MF(a2,B1_,acc[(BASE)+2][1]); acc[(BASE)+3][1]=MF(a3,B1_,acc[(BASE)+3][1]); \
    acc[(BASE)+0][2]=MF(a0,B2_,acc[(BASE)+0][2]); acc[(BASE)+1][2]=MF(a1,B2_,acc[(BASE)+1][2]); \
    acc[(BASE)+2][2]=MF(a2,B2_,acc[(BASE)+2][2]); acc[(BASE)+3][2]=MF(a3,B2_,acc[(BASE)+3][2]); \
    acc[(BASE)+0][3]=MF(a0,B3_,acc[(BASE)+0][3]); acc[(BASE)+1][3]=MF(a1,B3_,acc[(BASE)+1][3]); \
    acc[(BASE)+2][3]=MF(a2,B3_,acc[(BASE)+2][3]); acc[(BASE)+3][3]=MF(a3,B3_,acc[(BASE)+3][3]); \
    } while (0)

  const f32x4_t fzero = {0.f, 0.f, 0.f, 0.f};
  f32x4_t acc[8][4];
  #pragma unroll
  for (int m = 0; m < 8; ++m)
    #pragma unroll
    for (int n = 0; n < 4; ++n) acc[m][n] = fzero;

  int nk = K >> 6;

  // ---- prologue: stage A(0), B(0), B(1); confirm A(0),B(0) ------------------
  STAGE_A(0, 0); STAGE_A(0, 1);
  STAGE_B(0, 0); STAGE_B(0, 1);
  STAGE_B(1, 0); STAGE_B(1, 1);
  asm volatile("s_waitcnt vmcnt(4)" ::: "memory");
  BARX();

#define KTILE(D, KT) do { \
    bf16x8_t a0, a1, a2, a3; \
    bf16x8_t s0b0, s0b1, s0b2, s0b3, s1b0, s1b1, s1b2, s1b3; \
    /* P1: read b[s0], a[mh0,s0]; stage A-h0(kt+1); mfma mh0 x s0 */ \
    s0b0 = *(const AS3 bf16x8_t*)(bB0 + (D)*16384);          \
    s0b1 = *(const AS3 bf16x8_t*)(bB0 + (D)*16384 + 1024);   \
    s0b2 = *(const AS3 bf16x8_t*)(bB0 + (D)*16384 + 2048);   \
    s0b3 = *(const AS3 bf16x8_t*)(bB0 + (D)*16384 + 3072);   \
    LDA4(aB0, (D)*16384);                                    \
    if ((KT) + 1 < nk) STAGE_A((D)^1, 0);                    \
    BARX(); LGKM0();                                         \
    __builtin_amdgcn_s_setprio(1);                           \
    MFMA16(0, s0b0, s0b1, s0b2, s0b3);                       \
    __builtin_amdgcn_s_setprio(0);                           \
    BARX();                                                  \
    /* P2: read b[s1], a[mh1,s0]; stage A-h1(kt+1); mfma mh1 x s0 */ \
    s1b0 = *(const AS3 bf16x8_t*)(bB1 + (D)*16384);          \
    s1b1 = *(const AS3 bf16x8_t*)(bB1 + (D)*16384 + 1024);   \
    s1b2 = *(const AS3 bf16x8_t*)(bB1 + (D)*16384 + 2048);   \
    s1b3 = *(const AS3 bf16x8_t*)(bB1 + (D)*16384 + 3072);   \
    LDA4(aB0, (D)*16384 + 4096);                             \
    if ((KT) + 1 < nk) STAGE_A((D)^1, 1);                    \
    BARX(); LGKM0();                                         \
    __builtin_amdgcn_s_setprio(1);                           \
    MFMA16(4, s0b0, s0b1, s0b2, s0b3);                       \
    __builtin_amdgcn_s_setprio(0);                           \
    BARX();                                                  \
    /* P3: read a[mh0,s1]; stage B-h0(kt+2); mfma mh0 x s1 */ \
    LDA4(aB1, (D)*16384);                                    \
    if ((KT) + 2 < nk) STAGE_B((D), 0);                      \
    BARX(); LGKM0();                                         \
    __builtin_amdgcn_s_setprio(1);                           \
    MFMA16(0, s1b0, s1b1, s1b2, s1b3);                       \
    __builtin_amdgcn_s_setprio(0);                           \
    BARX();                                                  \
    /* P4: read a[mh1,s1]; stage B-h1(kt+2); mfma mh1 x s1; counted vmcnt */ \
    LDA4(aB1, (D)*16384 + 4096);                             \
    if ((KT) + 2 < nk) STAGE_B((D), 1);                      \
    BARX(); LGKM0();                                         \
    __builtin_amdgcn_s_setprio(1);                           \
    MFMA16(4, s1b0, s1b1, s1b2, s1b3);                       \
    __builtin_amdgcn_s_setprio(0);                           \
    if ((KT) + 2 < nk)      { asm volatile("s_waitcnt vmcnt(4)" ::: "memory"); } \
    else if ((KT) + 1 < nk) { asm volatile("s_waitcnt vmcnt(0)" ::: "memory"); } \
    BARX();                                                  \
  } while (0)

  for (int kt = 0; kt < nk; kt += 2) {
    KTILE(0, kt);
    KTILE(1, kt + 1);
  }

  // ---- epilogue -------------------------------------------------------------
  int rb0 = row0 + wr * 128 + hi * 4;
  int cb0 = col0 + wc * 64 + lr;
  float bv[4];
  #pragma unroll
  for (int n = 0; n < 4; ++n) bv[n] = (EPI != 0) ? bias[cb0 + n * 16] : 0.f;
  #pragma unroll
  for (int ar = 0; ar < 8; ++ar) {
    #pragma unroll
    for (int rr = 0; rr < 4; ++rr) {
      int row = rb0 + ar * 16 + rr;
      float ir = (EPI == 0) ? invrs[(long)bb * sR + row] : 0.f;
      #pragma unroll
      for (int n = 0; n < 4; ++n) {
        int col = cb0 + n * 16;
        float v = acc[ar][n][rr];
        long cidx = (long)bb * sC + (long)row * Nmat + col;
        if (EPI == 0) {
          ((float*)Cout)[cidx] = v * ir;
        } else if (EPI == 1) {
          ((unsigned short*)Cout)[cidx] = f2bf(gelu_fast(v + bv[n]));
        } else {
          ((float*)Cout)[cidx] = v + bv[n] + resid[(long)bb * sR + (long)row * Nmat + col];
        }
      }
    }
  }
#undef KTILE
#undef STAGE_A
#undef STAGE_B
#undef LDA4
#undef MFMA16
}

// ---- old 128x128 GEMM kept only for the N=64 s-FF2 tail ----------------------
template <int EPI>
__global__ __launch_bounds__(256, 2) void gemm128(
    const unsigned short* __restrict__ A, const unsigned short* __restrict__ BT,
    void* __restrict__ Cout, const float* __restrict__ bias,
    const float* __restrict__ resid, const float* __restrict__ invrs,
    int M, int Nmat, int K, long sA, long sB, long sC, long sR) {
  __shared__ unsigned short As[2][128 * 64];
  __shared__ unsigned short Bs[2][128 * 64];
  int tid = threadIdx.x, lane = tid & 63;
  int bj = blockIdx.x, bi = blockIdx.y, bb = blockIdx.z;
  const unsigned short* Ab = A + (long)bb * sA;
  const unsigned short* Bb = BT + (long)bb * sB;
  int row0 = bi * 128, col0 = bj * 128;
  int wid = tid >> 6, wr = wid >> 1, wc = wid & 1;
  const f32x4_t fzero = {0.f, 0.f, 0.f, 0.f};
  f32x4_t acc[4][4];
  #pragma unroll
  for (int m = 0; m < 4; ++m)
    #pragma unroll
    for (int n = 0; n < 4; ++n) acc[m][n] = fzero;

  auto stage = [&](int buf, int k0) {
    #pragma unroll
    for (int it = 0; it < 4; ++it) {
      int c = it * 256 + tid;
      int r = c >> 3, c8 = c & 7;
      gload16(Ab + (long)(row0 + r) * K + k0 + c8 * 8, &As[buf][(it * 256 + (tid & 192)) * 8]);
      int rr = col0 + r;
      if (rr >= Nmat) rr = Nmat - 1;
      gload16(Bb + (long)rr * K + k0 + c8 * 8, &Bs[buf][(it * 256 + (tid & 192)) * 8]);
    }
  };

  stage(0, 0);
  __syncthreads();

  int nk = K >> 6;
  for (int t = 0; t < nk; ++t) {
    int cur = t & 1;
    if (t + 1 < nk) stage(cur ^ 1, (t + 1) << 6);
    #pragma unroll
    for (int s2i = 0; s2i < 2; ++s2i) {
      bf16x8_t a[4], bfr[4];
      int lr = lane & 15, lk = s2i * 32 + (lane >> 4) * 8;
      #pragma unroll
      for (int m = 0; m < 4; ++m)
        a[m] = *(const bf16x8_t*)&As[cur][(wr * 64 + m * 16 + lr) * 64 + lk];
      #pragma unroll
      for (int n = 0; n < 4; ++n)
        bfr[n] = *(const bf16x8_t*)&Bs[cur][(wc * 64 + n * 16 + lr) * 64 + lk];
      #pragma unroll
      for (int m = 0; m < 4; ++m)
        #pragma unroll
        for (int n = 0; n < 4; ++n)
          acc[m][n] = __builtin_amdgcn_mfma_f32_16x16x32_bf16(a[m], bfr[n], acc[m][n], 0, 0, 0);
    }
    __syncthreads();
  }

  int rbase = row0 + wr * 64 + ((lane >> 4) << 2);
  int cbase = col0 + wc * 64 + (lane & 15);
  #pragma unroll
  for (int n = 0; n < 4; ++n) {
    int col = cbase + n * 16;
    if (col >= Nmat) continue;
    float bvv = (EPI != 0) ? bias[col] : 0.f;
    #pragma unroll
    for (int m = 0; m < 4; ++m) {
      #pragma unroll
      for (int r = 0; r < 4; ++r) {
        int row = rbase + m * 16 + r;
        float v = acc[m][n][r];
        long cidx = (long)bb * sC + (long)row * Nmat + col;
        if (EPI == 0) {
          v *= invrs[(long)bb * sR + row];
          ((float*)Cout)[cidx] = v;
        } else if (EPI == 1) {
          ((unsigned short*)Cout)[cidx] = f2bf(gelu_fast(v + bvv));
        } else {
          v += bvv + resid[(long)bb * sR + (long)row * Nmat + col];
          ((float*)Cout)[cidx] = v;
        }
      }
    }
  }
}

extern "C" void kernel_launch(void* const* d_in, const int* in_sizes, int n_in,
                              void* d_out, int out_size, void* d_ws, size_t ws_size,
                              hipStream_t stream) {
  (void)in_sizes; (void)n_in; (void)out_size; (void)ws_size;
  const float* in_z   = (const float*)d_in[0];
  const float* in_s   = (const float*)d_in[1];
  const float* lnz_sc = (const float*)d_in[2];
  const float* lnz_bi = (const float*)d_in[3];
  const float* lns_sc = (const float*)d_in[4];
  const float* lns_bi = (const float*)d_in[5];
  const float* Wz1 = (const float*)d_in[6];
  const float* bz1 = (const float*)d_in[7];
  const float* Wz2 = (const float*)d_in[8];
  const float* bz2 = (const float*)d_in[9];
  const float* Ws1 = (const float*)d_in[10];
  const float* bs1 = (const float*)d_in[11];
  const float* Ws2 = (const float*)d_in[12];
  const float* bs2 = (const float*)d_in[13];
  float* out_z = (float*)d_out;
  float* out_s = out_z + (long)ROWS * ZDIM;

  char* ws = (char*)d_ws;
  size_t off = 0;
  auto alloc = [&](size_t bytes) { void* p = ws + off; off += (bytes + 255) & ~(size_t)255; return p; };
  unsigned short* WH   = (unsigned short*)alloc((size_t)BATCH * NN * NN * 2); // w / h aliased
  unsigned short* ZT   = (unsigned short*)alloc((size_t)BATCH * ZDIM * NN * 2);
  unsigned short* XLN  = (unsigned short*)alloc((size_t)ROWS * ZDIM * 2);
  unsigned short* EBF  = (unsigned short*)alloc((size_t)ROWS * SDIM * 2);
  float* ZATT = (float*)alloc((size_t)ROWS * ZDIM * 4);
  float* ZBUF = (float*)alloc((size_t)ROWS * ZDIM * 4);
  float* SBUF = (float*)alloc((size_t)ROWS * SDIM * 4);
  float* SQ   = (float*)alloc((size_t)ROWS * 4);
  float* IRS  = (float*)alloc((size_t)ROWS * 4);
  unsigned short* W1Z = (unsigned short*)alloc((size_t)DEPTH * MLPD * ZDIM * 2);
  unsigned short* W2Z = (unsigned short*)alloc((size_t)DEPTH * ZDIM * MLPD * 2);
  unsigned short* W1S = (unsigned short*)alloc((size_t)DEPTH * MLPD * ZDIM * 2);
  unsigned short* W2S = (unsigned short*)alloc((size_t)DEPTH * SDIM * MLPD * 2);

  tconv_kernel<<<dim3(MLPD / 32, ZDIM / 32, DEPTH), dim3(32, 8), 0, stream>>>(
      Wz1, W1Z, ZDIM, MLPD, (long)ZDIM * MLPD, (long)MLPD * ZDIM);
  tconv_kernel<<<dim3(ZDIM / 32, MLPD / 32, DEPTH), dim3(32, 8), 0, stream>>>(
      Wz2, W2Z, MLPD, ZDIM, (long)MLPD * ZDIM, (long)ZDIM * MLPD);
  tconv_kernel<<<dim3(MLPD / 32, ZDIM / 32, DEPTH), dim3(32, 8), 0, stream>>>(
      Ws1, W1S, ZDIM, MLPD, (long)ZDIM * MLPD, (long)MLPD * ZDIM);
  tconv_kernel<<<dim3(SDIM / 32, MLPD / 32, DEPTH), dim3(32, 8), 0, stream>>>(
      Ws2, W2S, MLPD, SDIM, (long)MLPD * SDIM, (long)SDIM * MLPD);

  for (int L = 0; L < DEPTH; ++L) {
    const float* z_in = (L == 0) ? in_z : ZBUF;
    const float* s_in = (L == 0) ? in_s : SBUF;
    float* z_out = (L == DEPTH - 1) ? out_z : ZBUF;
    float* s_out = (L == DEPTH - 1) ? out_s : SBUF;

    conv_e_kernel<<<ROWS / 4, 256, 0, stream>>>(s_in, EBF, SQ);
    tconv_kernel<<<dim3(ZDIM / 32, NN / 32, BATCH), dim3(32, 8), 0, stream>>>(
        z_in, ZT, NN, ZDIM, (long)NN * ZDIM, (long)ZDIM * NN);
    attn_w_kernel<<<dim3(NN / 64, BATCH), 256, 0, stream>>>(EBF, SQ, WH, IRS);
    // z_att = (w @ z) / rowsum : M=NN, N=ZDIM, K=NN, batched
    gemm8p<0><<<dim3(ZDIM / 256, NN / 256, BATCH), 512, 0, stream>>>(
        WH, ZT, ZATT, nullptr, nullptr, IRS,
        ZDIM, NN, (long)NN * NN, (long)ZDIM * NN, (long)NN * ZDIM, NN);
    // z-FF
    ln_kernel<<<ROWS / 4, 256, 0, stream>>>(ZATT, lnz_sc + L * ZDIM, lnz_bi + L * ZDIM, XLN);
    gemm8p<1><<<dim3(MLPD / 256, ROWS / 256, 1), 512, 0, stream>>>(
        XLN, W1Z + (long)L * MLPD * ZDIM, WH, bz1 + L * MLPD, nullptr, nullptr,
        MLPD, ZDIM, 0, 0, 0, 0);
    gemm8p<2><<<dim3(ZDIM / 256, ROWS / 256, 1), 512, 0, stream>>>(
        WH, W2Z + (long)L * ZDIM * MLPD, z_out, bz2 + L * ZDIM, ZATT, nullptr,
        ZDIM, MLPD, 0, 0, 0, 0);
    // s-FF
    ln_kernel<<<ROWS / 4, 256, 0, stream>>>(z_out, lns_sc + L * ZDIM, lns_bi + L * ZDIM, XLN);
    gemm8p<1><<<dim3(MLPD / 256, ROWS / 256, 1), 512, 0, stream>>>(
        XLN, W1S + (long)L * MLPD * ZDIM, WH, bs1 + L * MLPD, nullptr, nullptr,
        MLPD, ZDIM, 0, 0, 0, 0);
    gemm128<2><<<dim3(1, ROWS / 128, 1), 256, 0, stream>>>(
        WH, W2S + (long)L * SDIM * MLPD, s_out, bs2 + L * SDIM, s_in, nullptr,
        ROWS, SDIM, MLPD, 0, 0, 0, 0);
  }
}